// Round 6
// baseline (511.666 us; speedup 1.0000x reference)
//
#include <hip/hip_runtime.h>

#define D 128
#define CAP 32
#define SPILL_MAX 65536

typedef unsigned int u32;
typedef unsigned short u16;
typedef __attribute__((ext_vector_type(8))) short bf16x8;
typedef __attribute__((ext_vector_type(4))) float f32x4;
typedef __attribute__((ext_vector_type(4))) u32 u32x4;

static __device__ __forceinline__ u16 f2bf(float x) {
    u32 u = __float_as_uint(x);
    u32 r = (u + 0x7fffu + ((u >> 16) & 1u)) >> 16;   // RNE
    return (u16)r;
}
static __device__ __forceinline__ float bf_lo(u32 u) { return __uint_as_float(u << 16); }
static __device__ __forceinline__ float bf_hi(u32 u) { return __uint_as_float(u & 0xffff0000u); }
static __device__ __forceinline__ u32 pack_bf(float lo, float hi) {
    return (u32)f2bf(lo) | ((u32)f2bf(hi) << 16);
}

// ---------------- mega prep: padded scatter | x->bf16 | weight concat ----------------
// One launch; grid partitioned by blockIdx. The latency-bound scatter blocks and the
// BW-bound conversion blocks co-schedule across CUs.

__global__ __launch_bounds__(256) void prep_kernel(
        const int* __restrict__ ei, int E, int EB,
        const float* __restrict__ x, u32* __restrict__ xb, int n8, int XB,
        const float* __restrict__ Wl0, const float* __restrict__ Wr0,
        const float* __restrict__ Wl1, const float* __restrict__ Wr1,
        const float* __restrict__ Wl2, const float* __restrict__ Wr2,
        u16* __restrict__ Wcat,
        int* __restrict__ cursor, int* __restrict__ col_pad,
        int* __restrict__ spill, int* __restrict__ spill_cnt) {
    int b = blockIdx.x;
    if (b < EB) {
        // single-pass CSR-pad scatter: rank via atomic, direct placement
        int e = b * 256 + threadIdx.x;
        if (e < E) {
            int d = ei[E + e];
            int s = ei[e];
            int r = atomicAdd(&cursor[d], 1);
            if (r < CAP) {
                __builtin_nontemporal_store(s, &col_pad[(size_t)d * CAP + r]);
            } else {
                int i = atomicAdd(spill_cnt, 1);
                if (i < SPILL_MAX) { spill[2 * i] = d; spill[2 * i + 1] = s; }
            }
        }
    } else if (b < EB + XB) {
        // x (f32) -> xb (bf16), 8 elems/thread
        int i = (b - EB) * 256 + threadIdx.x;
        if (i < n8) {
            const f32x4* p = (const f32x4*)x + (size_t)i * 2;
            f32x4 a = __builtin_nontemporal_load(p);
            f32x4 q = __builtin_nontemporal_load(p + 1);
            u32x4 o;
            o.x = pack_bf(a.x, a.y);
            o.y = pack_bf(a.z, a.w);
            o.z = pack_bf(q.x, q.y);
            o.w = pack_bf(q.z, q.w);
            ((u32x4*)xb)[i] = o;
        }
    } else {
        // Wcat_l[j][k] = (k<128 ? Wl[j][k] : Wr[j][k-128]), bf16, 3 layers
        int idx = (b - EB - XB) * 256 + threadIdx.x;
        if (idx < 3 * 32768) {
            int l = idx >> 15;
            int r = idx & 32767;
            int j = r >> 8, k = r & 255;
            const float* Wl = (l == 0) ? Wl0 : (l == 1) ? Wl1 : Wl2;
            const float* Wr = (l == 0) ? Wr0 : (l == 1) ? Wr1 : Wr2;
            float v = (k < 128) ? Wl[j * 128 + k] : Wr[j * 128 + (k - 128)];
            Wcat[idx] = f2bf(v);
        }
    }
}

// ---------------- mean aggregation: 2 nodes per wave, padded col ----------------
// Lane owns one u32 (2 channels). Both nodes' first 16 gathers issue back-to-back:
// 32 independent loads in flight per wave. Slots past deg are cndmask-masked.

template <int B>
static __device__ __forceinline__ void gather_pad(const u32* __restrict__ h32,
                                                  const int* __restrict__ cbase,
                                                  int t, int m, int lane,
                                                  float& ax, float& ay) {
    int c[B];
    #pragma unroll
    for (int q = 0; q < B; ++q) c[q] = (t + q < m) ? cbase[t + q] : 0;
    u32 u[B];
    #pragma unroll
    for (int q = 0; q < B; ++q) u[q] = h32[(size_t)c[q] * 64 + lane];
    #pragma unroll
    for (int q = 0; q < B; ++q) {
        u[q] = (t + q < m) ? u[q] : 0u;
        ax += bf_lo(u[q]);
        ay += bf_hi(u[q]);
    }
}

__global__ __launch_bounds__(256) void agg2_kernel(const u32* __restrict__ h32,  // [N][64]
                                                   const int* __restrict__ deg,
                                                   const int* __restrict__ col_pad,
                                                   const int* __restrict__ spill,
                                                   const int* __restrict__ spill_cnt,
                                                   u32* __restrict__ agg32, int N) {
    int lane = threadIdx.x & 63;
    int wid = threadIdx.x >> 6;
    int n0 = __builtin_amdgcn_readfirstlane(blockIdx.x * 8 + wid * 2);
    if (n0 >= N) return;
    int n1 = n0 + 1;
    bool v1 = (n1 < N);
    int d0 = __builtin_amdgcn_readfirstlane(deg[n0]);
    int d1 = v1 ? __builtin_amdgcn_readfirstlane(deg[n1]) : 0;
    int m0 = min(d0, CAP), m1 = min(d1, CAP);
    const int* c0 = col_pad + (size_t)n0 * CAP;
    const int* c1 = col_pad + (size_t)n1 * CAP;

    float ax0 = 0.f, ay0 = 0.f, ax1 = 0.f, ay1 = 0.f;
    gather_pad<16>(h32, c0, 0, m0, lane, ax0, ay0);
    if (v1) gather_pad<16>(h32, c1, 0, m1, lane, ax1, ay1);
    if (m0 > 16) gather_pad<16>(h32, c0, 16, m0, lane, ax0, ay0);
    if (m1 > 16) gather_pad<16>(h32, c1, 16, m1, lane, ax1, ay1);

    int sc = *spill_cnt;                       // ~0-50 entries in practice
    if (sc > 0) {
        for (int i = 0; i < sc; ++i) {
            int dd = spill[2 * i], ss = spill[2 * i + 1];
            if (dd == n0) { u32 u = h32[(size_t)ss * 64 + lane]; ax0 += bf_lo(u); ay0 += bf_hi(u); }
            if (v1 && dd == n1) { u32 u = h32[(size_t)ss * 64 + lane]; ax1 += bf_lo(u); ay1 += bf_hi(u); }
        }
    }

    float inv0 = 1.0f / fmaxf((float)d0, 1.0f);
    agg32[(size_t)n0 * 64 + lane] = pack_bf(ax0 * inv0, ay0 * inv0);
    if (v1) {
        float inv1 = 1.0f / fmaxf((float)d1, 1.0f);
        agg32[(size_t)n1 * 64 + lane] = pack_bf(ax1 * inv1, ay1 * inv1);
    }
}

// ---------------- fused dual GEMM via MFMA ----------------
// out[n,j] = [relu]( sum_k A[n,k]*Wcat[j,k] + bias[j] ),  A = [agg | h], K=256
// block: 256 thr = 4 waves; tile 64 rows x 128 cols; wave w: cols [w*32, w*32+32)

template <bool RELU, bool OUT_F32>
__global__ __launch_bounds__(256) void gemm_mfma(const u16* __restrict__ aggb,  // [N][128]
                                                 const u16* __restrict__ hb,    // [N][128]
                                                 const u16* __restrict__ Wcat,  // [128][256]
                                                 const float* __restrict__ bias,
                                                 u16* __restrict__ out_bf,
                                                 float* __restrict__ out_f32, int N) {
    __shared__ u16 s_a[64 * 256];   // 32 KB, XOR-swizzled rows
    int tid = threadIdx.x;
    int base = blockIdx.x * 64;
    int nrows = N - base; if (nrows > 64) nrows = 64;

    #pragma unroll
    for (int i = 0; i < 8; ++i) {
        int c = tid + i * 256;
        int row = c >> 5;
        int c16 = c & 31;
        int kbyte = (c16 * 16) ^ ((row & 7) << 4);
        uint4 v = make_uint4(0u, 0u, 0u, 0u);
        if (row < nrows) {
            const u16* src = (c16 < 16) ? (aggb + (size_t)(base + row) * 128 + c16 * 8)
                                        : (hb + (size_t)(base + row) * 128 + (c16 - 16) * 8);
            v = *(const uint4*)src;
        }
        *(uint4*)((char*)s_a + row * 512 + kbyte) = v;
    }
    __syncthreads();

    int lane = tid & 63;
    int wid = tid >> 6;
    int colbase = wid * 32;
    int jb = lane & 15;
    int kq = (lane >> 4) * 8;

    bf16x8 bfr[8][2];
    #pragma unroll
    for (int ks = 0; ks < 8; ++ks)
        #pragma unroll
        for (int n = 0; n < 2; ++n) {
            int j = colbase + n * 16 + jb;
            bfr[ks][n] = *(const bf16x8*)(Wcat + (size_t)j * 256 + ks * 32 + kq);
        }

    f32x4 acc[4][2];
    #pragma unroll
    for (int m = 0; m < 4; ++m)
        #pragma unroll
        for (int n = 0; n < 2; ++n)
            acc[m][n] = (f32x4){0.f, 0.f, 0.f, 0.f};

    #pragma unroll
    for (int ks = 0; ks < 8; ++ks) {
        bf16x8 afr[4];
        #pragma unroll
        for (int m = 0; m < 4; ++m) {
            int row = m * 16 + jb;
            int kbyte = (ks * 64 + kq * 2) ^ ((row & 7) << 4);
            afr[m] = *(const bf16x8*)((const char*)s_a + row * 512 + kbyte);
        }
        #pragma unroll
        for (int m = 0; m < 4; ++m)
            #pragma unroll
            for (int n = 0; n < 2; ++n)
                acc[m][n] = __builtin_amdgcn_mfma_f32_16x16x32_bf16(afr[m], bfr[ks][n],
                                                                    acc[m][n], 0, 0, 0);
    }

    float bv[2];
    #pragma unroll
    for (int n = 0; n < 2; ++n) bv[n] = bias[colbase + n * 16 + jb];

    #pragma unroll
    for (int m = 0; m < 4; ++m)
        #pragma unroll
        for (int n = 0; n < 2; ++n) {
            int colj = colbase + n * 16 + jb;
            #pragma unroll
            for (int r = 0; r < 4; ++r) {
                int row = m * 16 + (lane >> 4) * 4 + r;
                if (row < nrows) {
                    float v = acc[m][n][r] + bv[n];
                    if (RELU) v = fmaxf(v, 0.f);
                    size_t o = (size_t)(base + row) * 128 + colj;
                    if (OUT_F32) __builtin_nontemporal_store(v, &out_f32[o]);
                    else out_bf[o] = f2bf(v);
                }
            }
        }
}

// ---------------- launch ----------------

extern "C" void kernel_launch(void* const* d_in, const int* in_sizes, int n_in,
                              void* d_out, int out_size, void* d_ws, size_t ws_size,
                              hipStream_t stream) {
    const float* x   = (const float*)d_in[0];
    const int*   ei  = (const int*)d_in[1];
    const float* Wl0 = (const float*)d_in[2];
    const float* bl0 = (const float*)d_in[3];
    const float* Wr0 = (const float*)d_in[4];
    const float* Wl1 = (const float*)d_in[5];
    const float* bl1 = (const float*)d_in[6];
    const float* Wr1 = (const float*)d_in[7];
    const float* Wl2 = (const float*)d_in[8];
    const float* bl2 = (const float*)d_in[9];
    const float* Wr2 = (const float*)d_in[10];

    const int N = in_sizes[0] / D;
    const int E = in_sizes[1] / 2;

    char* ws = (char*)d_ws;
    size_t off = 0;
    auto alloc = [&](size_t bytes) {
        void* p = ws + off;
        off = (off + bytes + 255) & ~(size_t)255;
        return p;
    };
    u16* xb        = (u16*)alloc((size_t)N * D * 2);   // layer-0 input; reused as h2b
    u16* h1b       = (u16*)alloc((size_t)N * D * 2);
    u16* aggb      = (u16*)alloc((size_t)N * D * 2);
    u16* Wcat      = (u16*)alloc(3 * (size_t)D * 256 * 2);
    int* cursor    = (int*)alloc((size_t)N * 4);       // ends up = deg
    int* col_pad   = (int*)alloc((size_t)N * CAP * 4);
    int* spill     = (int*)alloc((size_t)SPILL_MAX * 2 * 4);
    int* spill_cnt = (int*)alloc(256);
    (void)ws_size; (void)n_in; (void)out_size;
    u16* h2b = xb;   // alias: xb dead after layer-1 GEMM

    hipMemsetAsync(cursor, 0, (size_t)N * 4, stream);
    hipMemsetAsync(spill_cnt, 0, 4, stream);

    const int n8 = N * D / 8;
    const int EB = (E + 255) / 256;
    const int XB = (n8 + 255) / 256;
    const int WB = (3 * 32768 + 255) / 256;
    prep_kernel<<<EB + XB + WB, 256, 0, stream>>>(ei, E, EB, x, (u32*)xb, n8, XB,
                                                  Wl0, Wr0, Wl1, Wr1, Wl2, Wr2, Wcat,
                                                  cursor, col_pad, spill, spill_cnt);

    float* out = (float*)d_out;
    int agrid = (N + 7) / 8;
    int ggrid = (N + 63) / 64;

    // layer 0: xb -> h1b (relu)
    agg2_kernel<<<agrid, 256, 0, stream>>>((const u32*)xb, cursor, col_pad, spill,
                                           spill_cnt, (u32*)aggb, N);
    gemm_mfma<true, false><<<ggrid, 256, 0, stream>>>(aggb, xb, Wcat + 0 * D * 256, bl0,
                                                      h1b, nullptr, N);
    // layer 1: h1b -> h2b (relu)
    agg2_kernel<<<agrid, 256, 0, stream>>>((const u32*)h1b, cursor, col_pad, spill,
                                           spill_cnt, (u32*)aggb, N);
    gemm_mfma<true, false><<<ggrid, 256, 0, stream>>>(aggb, h1b, Wcat + 1 * D * 256, bl1,
                                                      h2b, nullptr, N);
    // layer 2: h2b -> d_out (f32, no relu)
    agg2_kernel<<<agrid, 256, 0, stream>>>((const u32*)h2b, cursor, col_pad, spill,
                                           spill_cnt, (u32*)aggb, N);
    gemm_mfma<false, true><<<ggrid, 256, 0, stream>>>(aggb, h2b, Wcat + 2 * D * 256, bl2,
                                                      nullptr, out, N);
}

// Round 7
// 403.679 us; speedup vs baseline: 1.2675x; 1.2675x over previous
//
#include <hip/hip_runtime.h>

#define D 128

typedef unsigned int u32;
typedef unsigned short u16;
typedef __attribute__((ext_vector_type(8))) short bf16x8;
typedef __attribute__((ext_vector_type(4))) float f32x4;

static __device__ __forceinline__ u16 f2bf(float x) {
    u32 u = __float_as_uint(x);
    u32 r = (u + 0x7fffu + ((u >> 16) & 1u)) >> 16;   // RNE
    return (u16)r;
}
static __device__ __forceinline__ float bf_lo(u32 u) { return __uint_as_float(u << 16); }
static __device__ __forceinline__ float bf_hi(u32 u) { return __uint_as_float(u & 0xffff0000u); }
static __device__ __forceinline__ u32 pack_bf(float lo, float hi) {
    return (u32)f2bf(lo) | ((u32)f2bf(hi) << 16);
}

// ---------------- CSR build: rank + scan + place (round-4 proven) ----------------

__global__ void rank_count_kernel(const int* __restrict__ ei, int E,
                                  int* __restrict__ cursor, int* __restrict__ rank) {
    int e = blockIdx.x * blockDim.x + threadIdx.x;
    if (e < E) rank[e] = atomicAdd(&cursor[ei[E + e]], 1);
}

__global__ __launch_bounds__(1024) void scan_stage1(const int* __restrict__ deg, int N,
                                                    int* __restrict__ row_start,
                                                    int* __restrict__ partials) {
    __shared__ int wsum[16];
    int tid = threadIdx.x, lane = tid & 63, wid = tid >> 6;
    int i = blockIdx.x * 1024 + tid;
    int v = (i < N) ? deg[i] : 0;
    int x = v;
    #pragma unroll
    for (int off = 1; off < 64; off <<= 1) {
        int t = __shfl_up(x, off);
        if (lane >= off) x += t;
    }
    if (lane == 63) wsum[wid] = x;
    __syncthreads();
    if (tid == 0) {
        int acc = 0;
        #pragma unroll
        for (int w = 0; w < 16; ++w) { int t = wsum[w]; wsum[w] = acc; acc += t; }
        partials[blockIdx.x] = acc;
    }
    __syncthreads();
    if (i < N) row_start[i] = wsum[wid] + (x - v);
}

__global__ __launch_bounds__(1024) void scan_stage2(int* __restrict__ partials, int NB) {
    __shared__ int wsum[16];
    int tid = threadIdx.x, lane = tid & 63, wid = tid >> 6;
    int v = (tid < NB) ? partials[tid] : 0;
    int x = v;
    #pragma unroll
    for (int off = 1; off < 64; off <<= 1) {
        int t = __shfl_up(x, off);
        if (lane >= off) x += t;
    }
    if (lane == 63) wsum[wid] = x;
    __syncthreads();
    if (tid == 0) {
        int acc = 0;
        #pragma unroll
        for (int w = 0; w < 16; ++w) { int t = wsum[w]; wsum[w] = acc; acc += t; }
        partials[NB] = acc;
    }
    __syncthreads();
    if (tid < NB) partials[tid] = wsum[wid] + (x - v);
}

__global__ __launch_bounds__(1024) void scan_stage3(int* __restrict__ row_start,
                                                    const int* __restrict__ partials,
                                                    int N, int NB) {
    int i = blockIdx.x * 1024 + threadIdx.x;
    if (i < N) row_start[i] += partials[blockIdx.x];
    if (i == 0) row_start[N] = partials[NB];
}

__global__ void place_kernel(const int* __restrict__ ei, int E,
                             const int* __restrict__ row_start,
                             const int* __restrict__ rank, int* __restrict__ col) {
    int e = blockIdx.x * blockDim.x + threadIdx.x;
    if (e < E) {
        int d = ei[E + e];
        __builtin_nontemporal_store(ei[e], &col[row_start[d] + rank[e]]);
    }
}

// ---------------- conversions ----------------

__global__ void to_bf16_kernel(const float* __restrict__ in, u32* __restrict__ out, int n8) {
    int i = blockIdx.x * 256 + threadIdx.x;
    if (i >= n8) return;
    const float4* p = (const float4*)in + (size_t)i * 2;
    float4 a = p[0], b = p[1];
    uint4 o;
    o.x = pack_bf(a.x, a.y);
    o.y = pack_bf(a.z, a.w);
    o.z = pack_bf(b.x, b.y);
    o.w = pack_bf(b.z, b.w);
    ((uint4*)out)[i] = o;
}

__global__ void build_wcat_all(const float* __restrict__ Wl0, const float* __restrict__ Wr0,
                               const float* __restrict__ Wl1, const float* __restrict__ Wr1,
                               const float* __restrict__ Wl2, const float* __restrict__ Wr2,
                               u16* __restrict__ Wcat) {
    int idx = blockIdx.x * 256 + threadIdx.x;   // 3*32768 total
    int l = idx >> 15;
    int r = idx & 32767;
    int j = r >> 8, k = r & 255;
    const float* Wl = (l == 0) ? Wl0 : (l == 1) ? Wl1 : Wl2;
    const float* Wr = (l == 0) ? Wr0 : (l == 1) ? Wr1 : Wr2;
    float v = (k < 128) ? Wl[j * 128 + k] : Wr[j * 128 + (k - 128)];
    Wcat[idx] = f2bf(v);
}

// ---------------- mean aggregation: pair-gather ----------------
// One wave per node; lane reads uint2 (4 channels). Lanes 0-31 fetch neighbor p's
// row, lanes 32-63 fetch neighbor p+1's row -> 2 neighbors per load instruction.
// Exact pair ladder 8/4/2/1 (+odd remainder, predicated). Cross-half shfl_xor(32)
// reduce at the end; lanes 0-31 write the row.

template <int B>
static __device__ __forceinline__ void gather_pairs(const uint2* __restrict__ h2,
                                                    const int* __restrict__ col,
                                                    int p, int half, int l32,
                                                    float& a0, float& a1,
                                                    float& a2, float& a3) {
    int c[B];
    #pragma unroll
    for (int q = 0; q < B; ++q) c[q] = col[p + 2 * q + half];
    uint2 u[B];
    #pragma unroll
    for (int q = 0; q < B; ++q) u[q] = h2[(size_t)c[q] * 32 + l32];
    #pragma unroll
    for (int q = 0; q < B; ++q) {
        a0 += bf_lo(u[q].x); a1 += bf_hi(u[q].x);
        a2 += bf_lo(u[q].y); a3 += bf_hi(u[q].y);
    }
}

__global__ __launch_bounds__(256) void agg_pair(const uint2* __restrict__ h2,   // [N][32]
                                                const int* __restrict__ row_start,
                                                const int* __restrict__ col,
                                                uint2* __restrict__ agg2, int N) {
    int node = blockIdx.x * 4 + (threadIdx.x >> 6);
    node = __builtin_amdgcn_readfirstlane(node);
    if (node >= N) return;
    int lane = threadIdx.x & 63;
    int half = lane >> 5;
    int l32 = lane & 31;
    int s0 = row_start[node], s1 = row_start[node + 1];

    float a0 = 0.f, a1 = 0.f, a2 = 0.f, a3 = 0.f;
    int p = s0;
    while (p + 16 <= s1) { gather_pairs<8>(h2, col, p, half, l32, a0, a1, a2, a3); p += 16; }
    if (p + 8 <= s1)     { gather_pairs<4>(h2, col, p, half, l32, a0, a1, a2, a3); p += 8; }
    if (p + 4 <= s1)     { gather_pairs<2>(h2, col, p, half, l32, a0, a1, a2, a3); p += 4; }
    if (p + 2 <= s1)     { gather_pairs<1>(h2, col, p, half, l32, a0, a1, a2, a3); p += 2; }
    if (p < s1) {
        // one remaining neighbor: both halves load its row, only half 0 accumulates
        int c = col[p];
        uint2 u = h2[(size_t)c * 32 + l32];
        u32 ux = half ? 0u : u.x;
        u32 uy = half ? 0u : u.y;
        a0 += bf_lo(ux); a1 += bf_hi(ux);
        a2 += bf_lo(uy); a3 += bf_hi(uy);
    }

    // combine even-neighbor partials (half 0) with odd-neighbor partials (half 1)
    a0 += __shfl_xor(a0, 32);
    a1 += __shfl_xor(a1, 32);
    a2 += __shfl_xor(a2, 32);
    a3 += __shfl_xor(a3, 32);

    if (half == 0) {
        float inv = 1.0f / fmaxf((float)(s1 - s0), 1.0f);
        uint2 o;
        o.x = pack_bf(a0 * inv, a1 * inv);
        o.y = pack_bf(a2 * inv, a3 * inv);
        agg2[(size_t)node * 32 + l32] = o;
    }
}

// ---------------- fused dual GEMM via MFMA ----------------
// out[n,j] = [relu]( sum_k A[n,k]*Wcat[j,k] + bias[j] ),  A = [agg | h], K=256
// block: 256 thr = 4 waves; tile 64 rows x 128 cols; wave w: cols [w*32, w*32+32)

template <bool RELU, bool OUT_F32>
__global__ __launch_bounds__(256) void gemm_mfma(const u16* __restrict__ aggb,  // [N][128]
                                                 const u16* __restrict__ hb,    // [N][128]
                                                 const u16* __restrict__ Wcat,  // [128][256]
                                                 const float* __restrict__ bias,
                                                 u16* __restrict__ out_bf,
                                                 float* __restrict__ out_f32, int N) {
    __shared__ u16 s_a[64 * 256];   // 32 KB, XOR-swizzled rows
    int tid = threadIdx.x;
    int base = blockIdx.x * 64;
    int nrows = N - base; if (nrows > 64) nrows = 64;

    #pragma unroll
    for (int i = 0; i < 8; ++i) {
        int c = tid + i * 256;
        int row = c >> 5;
        int c16 = c & 31;
        int kbyte = (c16 * 16) ^ ((row & 7) << 4);
        uint4 v = make_uint4(0u, 0u, 0u, 0u);
        if (row < nrows) {
            const u16* src = (c16 < 16) ? (aggb + (size_t)(base + row) * 128 + c16 * 8)
                                        : (hb + (size_t)(base + row) * 128 + (c16 - 16) * 8);
            v = *(const uint4*)src;
        }
        *(uint4*)((char*)s_a + row * 512 + kbyte) = v;
    }
    __syncthreads();

    int lane = tid & 63;
    int wid = tid >> 6;
    int colbase = wid * 32;
    int jb = lane & 15;
    int kq = (lane >> 4) * 8;

    bf16x8 bfr[8][2];
    #pragma unroll
    for (int ks = 0; ks < 8; ++ks)
        #pragma unroll
        for (int n = 0; n < 2; ++n) {
            int j = colbase + n * 16 + jb;
            bfr[ks][n] = *(const bf16x8*)(Wcat + (size_t)j * 256 + ks * 32 + kq);
        }

    f32x4 acc[4][2];
    #pragma unroll
    for (int m = 0; m < 4; ++m)
        #pragma unroll
        for (int n = 0; n < 2; ++n)
            acc[m][n] = (f32x4){0.f, 0.f, 0.f, 0.f};

    #pragma unroll
    for (int ks = 0; ks < 8; ++ks) {
        bf16x8 afr[4];
        #pragma unroll
        for (int m = 0; m < 4; ++m) {
            int row = m * 16 + jb;
            int kbyte = (ks * 64 + kq * 2) ^ ((row & 7) << 4);
            afr[m] = *(const bf16x8*)((const char*)s_a + row * 512 + kbyte);
        }
        #pragma unroll
        for (int m = 0; m < 4; ++m)
            #pragma unroll
            for (int n = 0; n < 2; ++n)
                acc[m][n] = __builtin_amdgcn_mfma_f32_16x16x32_bf16(afr[m], bfr[ks][n],
                                                                    acc[m][n], 0, 0, 0);
    }

    float bv[2];
    #pragma unroll
    for (int n = 0; n < 2; ++n) bv[n] = bias[colbase + n * 16 + jb];

    #pragma unroll
    for (int m = 0; m < 4; ++m)
        #pragma unroll
        for (int n = 0; n < 2; ++n) {
            int colj = colbase + n * 16 + jb;
            #pragma unroll
            for (int r = 0; r < 4; ++r) {
                int row = m * 16 + (lane >> 4) * 4 + r;
                if (row < nrows) {
                    float v = acc[m][n][r] + bv[n];
                    if (RELU) v = fmaxf(v, 0.f);
                    size_t o = (size_t)(base + row) * 128 + colj;
                    if (OUT_F32) __builtin_nontemporal_store(v, &out_f32[o]);
                    else out_bf[o] = f2bf(v);
                }
            }
        }
}

// ---------------- launch ----------------

extern "C" void kernel_launch(void* const* d_in, const int* in_sizes, int n_in,
                              void* d_out, int out_size, void* d_ws, size_t ws_size,
                              hipStream_t stream) {
    const float* x   = (const float*)d_in[0];
    const int*   ei  = (const int*)d_in[1];
    const float* Wl0 = (const float*)d_in[2];
    const float* bl0 = (const float*)d_in[3];
    const float* Wr0 = (const float*)d_in[4];
    const float* Wl1 = (const float*)d_in[5];
    const float* bl1 = (const float*)d_in[6];
    const float* Wr1 = (const float*)d_in[7];
    const float* Wl2 = (const float*)d_in[8];
    const float* bl2 = (const float*)d_in[9];
    const float* Wr2 = (const float*)d_in[10];

    const int N = in_sizes[0] / D;
    const int E = in_sizes[1] / 2;
    const int NB = (N + 1023) / 1024;

    char* ws = (char*)d_ws;
    size_t off = 0;
    auto alloc = [&](size_t bytes) {
        void* p = ws + off;
        off = (off + bytes + 255) & ~(size_t)255;
        return p;
    };
    u16* xb        = (u16*)alloc((size_t)N * D * 2);   // layer-0 input; reused as h2b
    u16* h1b       = (u16*)alloc((size_t)N * D * 2);
    u16* aggb      = (u16*)alloc((size_t)N * D * 2);
    u16* Wcat      = (u16*)alloc(3 * (size_t)D * 256 * 2);
    int* cursor    = (int*)alloc((size_t)N * 4);       // ends up = deg
    int* row_start = (int*)alloc((size_t)(N + 1) * 4);
    int* partials  = (int*)alloc((size_t)(NB + 1) * 4);
    int* rank      = (int*)alloc((size_t)E * 4);
    int* colv      = (int*)alloc((size_t)E * 4);
    (void)ws_size; (void)n_in; (void)out_size;
    u16* h2b = xb;   // alias: xb dead after layer-1 GEMM

    hipMemsetAsync(cursor, 0, (size_t)N * 4, stream);

    build_wcat_all<<<384, 256, 0, stream>>>(Wl0, Wr0, Wl1, Wr1, Wl2, Wr2, Wcat);

    int n8 = N * D / 8;
    to_bf16_kernel<<<(n8 + 255) / 256, 256, 0, stream>>>(x, (u32*)xb, n8);

    // CSR
    int eb = (E + 255) / 256;
    rank_count_kernel<<<eb, 256, 0, stream>>>(ei, E, cursor, rank);
    scan_stage1<<<NB, 1024, 0, stream>>>(cursor, N, row_start, partials);
    scan_stage2<<<1, 1024, 0, stream>>>(partials, NB);
    scan_stage3<<<NB, 1024, 0, stream>>>(row_start, partials, N, NB);
    place_kernel<<<eb, 256, 0, stream>>>(ei, E, row_start, rank, colv);

    float* out = (float*)d_out;
    int agrid = (N + 3) / 4;
    int ggrid = (N + 63) / 64;

    // layer 0: xb -> h1b (relu)
    agg_pair<<<agrid, 256, 0, stream>>>((const uint2*)xb, row_start, colv,
                                        (uint2*)aggb, N);
    gemm_mfma<true, false><<<ggrid, 256, 0, stream>>>(aggb, xb, Wcat + 0 * D * 256, bl0,
                                                      h1b, nullptr, N);
    // layer 1: h1b -> h2b (relu)
    agg_pair<<<agrid, 256, 0, stream>>>((const uint2*)h1b, row_start, colv,
                                        (uint2*)aggb, N);
    gemm_mfma<true, false><<<ggrid, 256, 0, stream>>>(aggb, h1b, Wcat + 1 * D * 256, bl1,
                                                      h2b, nullptr, N);
    // layer 2: h2b -> d_out (f32, no relu)
    agg_pair<<<agrid, 256, 0, stream>>>((const uint2*)h2b, row_start, colv,
                                        (uint2*)aggb, N);
    gemm_mfma<false, true><<<ggrid, 256, 0, stream>>>(aggb, h2b, Wcat + 2 * D * 256, bl2,
                                                      nullptr, out, N);
}

// Round 8
// 346.426 us; speedup vs baseline: 1.4770x; 1.1653x over previous
//
#include <hip/hip_runtime.h>

#define D 128
#define BSHIFT 7          // 128 nodes per bucket
#define EPB 8192          // edges per s1/s2 block (1024 threads x 8)

typedef unsigned int u32;
typedef unsigned short u16;
typedef unsigned long long u64;
typedef __attribute__((ext_vector_type(8))) short bf16x8;
typedef __attribute__((ext_vector_type(4))) float f32x4;

static __device__ __forceinline__ u16 f2bf(float x) {
    u32 u = __float_as_uint(x);
    u32 r = (u + 0x7fffu + ((u >> 16) & 1u)) >> 16;   // RNE
    return (u16)r;
}
static __device__ __forceinline__ float bf_lo(u32 u) { return __uint_as_float(u << 16); }
static __device__ __forceinline__ float bf_hi(u32 u) { return __uint_as_float(u & 0xffff0000u); }
static __device__ __forceinline__ u32 pack_bf(float lo, float hi) {
    return (u32)f2bf(lo) | ((u32)f2bf(hi) << 16);
}

// ---------------- CSR build via bucket counting-sort ----------------
// bucket b = dst >> BSHIFT. s1: per-block LDS hist -> global bucket counts +
// per-(block,bucket) base. scan: bucket starts. s2: scatter (dst,src) u64 pairs
// bucket-major. s3: per-bucket LDS histogram/scan -> row_start + col (coalesced).

__global__ __launch_bounds__(1024) void s1_hist(const int* __restrict__ ei, int E, int NBUCK,
                                                int* __restrict__ gcnt,
                                                int* __restrict__ blockbase) {
    __shared__ int lh[1024];
    int tid = threadIdx.x;
    for (int b = tid; b < NBUCK; b += 1024) lh[b] = 0;
    __syncthreads();
    int base = blockIdx.x * EPB;
    #pragma unroll
    for (int i = 0; i < EPB / 1024; ++i) {
        int e = base + i * 1024 + tid;
        if (e < E) atomicAdd(&lh[ei[E + e] >> BSHIFT], 1);
    }
    __syncthreads();
    for (int b = tid; b < NBUCK; b += 1024) {
        int c = lh[b];
        int g = atomicAdd(&gcnt[b], c);
        blockbase[(size_t)blockIdx.x * NBUCK + b] = g;
    }
}

__global__ __launch_bounds__(1024) void bucket_scan(const int* __restrict__ gcnt,
                                                    int* __restrict__ bstart, int NBUCK) {
    __shared__ int wsum[16];
    int tid = threadIdx.x, lane = tid & 63, wid = tid >> 6;
    int v = (tid < NBUCK) ? gcnt[tid] : 0;
    int x = v;
    #pragma unroll
    for (int off = 1; off < 64; off <<= 1) {
        int t = __shfl_up(x, off);
        if (lane >= off) x += t;
    }
    if (lane == 63) wsum[wid] = x;
    __syncthreads();
    if (tid == 0) {
        int acc = 0;
        #pragma unroll
        for (int w = 0; w < 16; ++w) { int t = wsum[w]; wsum[w] = acc; acc += t; }
        bstart[NBUCK] = acc;            // total = E
    }
    __syncthreads();
    if (tid < NBUCK) bstart[tid] = wsum[wid] + (x - v);
}

__global__ __launch_bounds__(1024) void s2_scatter(const int* __restrict__ ei, int E, int NBUCK,
                                                   const int* __restrict__ bstart,
                                                   const int* __restrict__ blockbase,
                                                   u64* __restrict__ pairs) {
    __shared__ int lh[1024];
    __shared__ int bb[1024];
    int tid = threadIdx.x;
    for (int b = tid; b < NBUCK; b += 1024) {
        lh[b] = 0;
        bb[b] = bstart[b] + blockbase[(size_t)blockIdx.x * NBUCK + b];
    }
    __syncthreads();
    int base = blockIdx.x * EPB;
    #pragma unroll
    for (int i = 0; i < EPB / 1024; ++i) {
        int e = base + i * 1024 + tid;
        if (e < E) {
            int d = ei[E + e];
            int s = ei[e];
            int b = d >> BSHIFT;
            int l = atomicAdd(&lh[b], 1);
            u64 pr = (u64)(u32)d | ((u64)(u32)s << 32);
            __builtin_nontemporal_store(pr, &pairs[bb[b] + l]);
        }
    }
}

__global__ __launch_bounds__(256) void s3_csr(const u64* __restrict__ pairs,
                                              const int* __restrict__ bstart,
                                              int* __restrict__ row_start,
                                              int* __restrict__ col, int N, int NBUCK) {
    __shared__ int lcnt[128];
    __shared__ int lstart[128];
    int b = blockIdx.x;
    int tid = threadIdx.x;
    int bs = bstart[b], be = bstart[b + 1];
    int cnt = be - bs;
    int node_base = b << BSHIFT;
    if (tid < 128) lcnt[tid] = 0;
    __syncthreads();
    for (int i = tid; i < cnt; i += 256)
        atomicAdd(&lcnt[(int)(u32)pairs[bs + i] - node_base], 1);
    __syncthreads();
    if (tid == 0) {
        int acc = 0;
        for (int t = 0; t < 128; ++t) { lstart[t] = acc; acc += lcnt[t]; }
    }
    __syncthreads();
    if (tid < 128) {
        int node = node_base + tid;
        if (node < N) row_start[node] = bs + lstart[tid];
        lcnt[tid] = 0;                   // reuse as cursor
    }
    if (b == NBUCK - 1 && tid == 0) row_start[N] = be;
    __syncthreads();
    for (int i = tid; i < cnt; i += 256) {
        u64 pr = pairs[bs + i];
        int ld = (int)(u32)pr - node_base;
        int l = atomicAdd(&lcnt[ld], 1);
        col[bs + lstart[ld] + l] = (int)(u32)(pr >> 32);
    }
}

// ---------------- conversions ----------------

__global__ void to_bf16_kernel(const float* __restrict__ in, u32* __restrict__ out, int n8) {
    int i = blockIdx.x * 256 + threadIdx.x;
    if (i >= n8) return;
    const float4* p = (const float4*)in + (size_t)i * 2;
    float4 a = p[0], b = p[1];
    uint4 o;
    o.x = pack_bf(a.x, a.y);
    o.y = pack_bf(a.z, a.w);
    o.z = pack_bf(b.x, b.y);
    o.w = pack_bf(b.z, b.w);
    ((uint4*)out)[i] = o;
}

__global__ void build_wcat_all(const float* __restrict__ Wl0, const float* __restrict__ Wr0,
                               const float* __restrict__ Wl1, const float* __restrict__ Wr1,
                               const float* __restrict__ Wl2, const float* __restrict__ Wr2,
                               u16* __restrict__ Wcat) {
    int idx = blockIdx.x * 256 + threadIdx.x;   // 3*32768 total
    int l = idx >> 15;
    int r = idx & 32767;
    int j = r >> 8, k = r & 255;
    const float* Wl = (l == 0) ? Wl0 : (l == 1) ? Wl1 : Wl2;
    const float* Wr = (l == 0) ? Wr0 : (l == 1) ? Wr1 : Wr2;
    float v = (k < 128) ? Wl[j * 128 + k] : Wr[j * 128 + (k - 128)];
    Wcat[idx] = f2bf(v);
}

// ---------------- mean aggregation (round-4 proven ladder) ----------------

template <int B>
static __device__ __forceinline__ void gather_batch(const u32* __restrict__ h32,
                                                    const int* __restrict__ col,
                                                    int p, int lane,
                                                    float& ax, float& ay) {
    int c[B];
    #pragma unroll
    for (int q = 0; q < B; ++q) c[q] = col[p + q];
    u32 u[B];
    #pragma unroll
    for (int q = 0; q < B; ++q) u[q] = h32[(size_t)c[q] * 64 + lane];
    #pragma unroll
    for (int q = 0; q < B; ++q) { ax += bf_lo(u[q]); ay += bf_hi(u[q]); }
}

__global__ __launch_bounds__(256) void agg_bf16(const u32* __restrict__ h32,   // [N][64]
                                                const int* __restrict__ row_start,
                                                const int* __restrict__ col,
                                                u32* __restrict__ agg32, int N) {
    int node = blockIdx.x * 4 + (threadIdx.x >> 6);
    node = __builtin_amdgcn_readfirstlane(node);
    if (node >= N) return;
    int lane = threadIdx.x & 63;
    int s0 = row_start[node], s1 = row_start[node + 1];
    float ax = 0.f, ay = 0.f;
    int p = s0;
    while (p + 16 <= s1) { gather_batch<16>(h32, col, p, lane, ax, ay); p += 16; }
    if (p + 8 <= s1)     { gather_batch<8>(h32, col, p, lane, ax, ay);  p += 8; }
    if (p + 4 <= s1)     { gather_batch<4>(h32, col, p, lane, ax, ay);  p += 4; }
    if (p + 2 <= s1)     { gather_batch<2>(h32, col, p, lane, ax, ay);  p += 2; }
    if (p < s1)          { gather_batch<1>(h32, col, p, lane, ax, ay); }
    float inv = 1.0f / fmaxf((float)(s1 - s0), 1.0f);
    agg32[(size_t)node * 64 + lane] = pack_bf(ax * inv, ay * inv);
}

// ---------------- fused dual GEMM via MFMA ----------------
// out[n,j] = [relu]( sum_k A[n,k]*Wcat[j,k] + bias[j] ),  A = [agg | h], K=256
// block: 256 thr = 4 waves; tile 64 rows x 128 cols; wave w: cols [w*32, w*32+32)

template <bool RELU, bool OUT_F32>
__global__ __launch_bounds__(256) void gemm_mfma(const u16* __restrict__ aggb,  // [N][128]
                                                 const u16* __restrict__ hb,    // [N][128]
                                                 const u16* __restrict__ Wcat,  // [128][256]
                                                 const float* __restrict__ bias,
                                                 u16* __restrict__ out_bf,
                                                 float* __restrict__ out_f32, int N) {
    __shared__ u16 s_a[64 * 256];   // 32 KB, XOR-swizzled rows
    int tid = threadIdx.x;
    int base = blockIdx.x * 64;
    int nrows = N - base; if (nrows > 64) nrows = 64;

    #pragma unroll
    for (int i = 0; i < 8; ++i) {
        int c = tid + i * 256;
        int row = c >> 5;
        int c16 = c & 31;
        int kbyte = (c16 * 16) ^ ((row & 7) << 4);
        uint4 v = make_uint4(0u, 0u, 0u, 0u);
        if (row < nrows) {
            const u16* src = (c16 < 16) ? (aggb + (size_t)(base + row) * 128 + c16 * 8)
                                        : (hb + (size_t)(base + row) * 128 + (c16 - 16) * 8);
            v = *(const uint4*)src;
        }
        *(uint4*)((char*)s_a + row * 512 + kbyte) = v;
    }
    __syncthreads();

    int lane = tid & 63;
    int wid = tid >> 6;
    int colbase = wid * 32;
    int jb = lane & 15;
    int kq = (lane >> 4) * 8;

    bf16x8 bfr[8][2];
    #pragma unroll
    for (int ks = 0; ks < 8; ++ks)
        #pragma unroll
        for (int n = 0; n < 2; ++n) {
            int j = colbase + n * 16 + jb;
            bfr[ks][n] = *(const bf16x8*)(Wcat + (size_t)j * 256 + ks * 32 + kq);
        }

    f32x4 acc[4][2];
    #pragma unroll
    for (int m = 0; m < 4; ++m)
        #pragma unroll
        for (int n = 0; n < 2; ++n)
            acc[m][n] = (f32x4){0.f, 0.f, 0.f, 0.f};

    #pragma unroll
    for (int ks = 0; ks < 8; ++ks) {
        bf16x8 afr[4];
        #pragma unroll
        for (int m = 0; m < 4; ++m) {
            int row = m * 16 + jb;
            int kbyte = (ks * 64 + kq * 2) ^ ((row & 7) << 4);
            afr[m] = *(const bf16x8*)((const char*)s_a + row * 512 + kbyte);
        }
        #pragma unroll
        for (int m = 0; m < 4; ++m)
            #pragma unroll
            for (int n = 0; n < 2; ++n)
                acc[m][n] = __builtin_amdgcn_mfma_f32_16x16x32_bf16(afr[m], bfr[ks][n],
                                                                    acc[m][n], 0, 0, 0);
    }

    float bv[2];
    #pragma unroll
    for (int n = 0; n < 2; ++n) bv[n] = bias[colbase + n * 16 + jb];

    #pragma unroll
    for (int m = 0; m < 4; ++m)
        #pragma unroll
        for (int n = 0; n < 2; ++n) {
            int colj = colbase + n * 16 + jb;
            #pragma unroll
            for (int r = 0; r < 4; ++r) {
                int row = m * 16 + (lane >> 4) * 4 + r;
                if (row < nrows) {
                    float v = acc[m][n][r] + bv[n];
                    if (RELU) v = fmaxf(v, 0.f);
                    size_t o = (size_t)(base + row) * 128 + colj;
                    if (OUT_F32) __builtin_nontemporal_store(v, &out_f32[o]);
                    else out_bf[o] = f2bf(v);
                }
            }
        }
}

// ---------------- launch ----------------

extern "C" void kernel_launch(void* const* d_in, const int* in_sizes, int n_in,
                              void* d_out, int out_size, void* d_ws, size_t ws_size,
                              hipStream_t stream) {
    const float* x   = (const float*)d_in[0];
    const int*   ei  = (const int*)d_in[1];
    const float* Wl0 = (const float*)d_in[2];
    const float* bl0 = (const float*)d_in[3];
    const float* Wr0 = (const float*)d_in[4];
    const float* Wl1 = (const float*)d_in[5];
    const float* bl1 = (const float*)d_in[6];
    const float* Wr1 = (const float*)d_in[7];
    const float* Wl2 = (const float*)d_in[8];
    const float* bl2 = (const float*)d_in[9];
    const float* Wr2 = (const float*)d_in[10];

    const int N = in_sizes[0] / D;
    const int E = in_sizes[1] / 2;
    const int NBUCK = (N + 127) >> BSHIFT;          // <=1024 for N<=131072
    const int SB = (E + EPB - 1) / EPB;             // s1/s2 grid

    char* ws = (char*)d_ws;
    size_t off = 0;
    auto alloc = [&](size_t bytes) {
        void* p = ws + off;
        off = (off + bytes + 255) & ~(size_t)255;
        return p;
    };
    u16* xb        = (u16*)alloc((size_t)N * D * 2);   // layer-0 input; reused as h2b
    u16* h1b       = (u16*)alloc((size_t)N * D * 2);
    u16* aggb      = (u16*)alloc((size_t)N * D * 2);   // also aliases `pairs` pre-agg
    u16* Wcat      = (u16*)alloc(3 * (size_t)D * 256 * 2);
    int* gcnt      = (int*)alloc((size_t)NBUCK * 4);
    int* bstart    = (int*)alloc((size_t)(NBUCK + 1) * 4);
    int* blockbase = (int*)alloc((size_t)SB * NBUCK * 4);
    int* row_start = (int*)alloc((size_t)(N + 1) * 4);
    int* colv      = (int*)alloc((size_t)E * 4);
    (void)ws_size; (void)n_in; (void)out_size;
    u16* h2b = xb;                 // alias: xb dead after layer-1 GEMM
    u64* pairs = (u64*)aggb;       // alias: pairs dead before first agg write

    hipMemsetAsync(gcnt, 0, (size_t)NBUCK * 4, stream);

    build_wcat_all<<<384, 256, 0, stream>>>(Wl0, Wr0, Wl1, Wr1, Wl2, Wr2, Wcat);

    int n8 = N * D / 8;
    to_bf16_kernel<<<(n8 + 255) / 256, 256, 0, stream>>>(x, (u32*)xb, n8);

    // CSR via counting sort
    s1_hist<<<SB, 1024, 0, stream>>>(ei, E, NBUCK, gcnt, blockbase);
    bucket_scan<<<1, 1024, 0, stream>>>(gcnt, bstart, NBUCK);
    s2_scatter<<<SB, 1024, 0, stream>>>(ei, E, NBUCK, bstart, blockbase, pairs);
    s3_csr<<<NBUCK, 256, 0, stream>>>(pairs, bstart, row_start, colv, N, NBUCK);

    float* out = (float*)d_out;
    int agrid = (N + 3) / 4;
    int ggrid = (N + 63) / 64;

    // layer 0: xb -> h1b (relu)
    agg_bf16<<<agrid, 256, 0, stream>>>((const u32*)xb, row_start, colv, (u32*)aggb, N);
    gemm_mfma<true, false><<<ggrid, 256, 0, stream>>>(aggb, xb, Wcat + 0 * D * 256, bl0,
                                                      h1b, nullptr, N);
    // layer 1: h1b -> h2b (relu)
    agg_bf16<<<agrid, 256, 0, stream>>>((const u32*)h1b, row_start, colv, (u32*)aggb, N);
    gemm_mfma<true, false><<<ggrid, 256, 0, stream>>>(aggb, h1b, Wcat + 1 * D * 256, bl1,
                                                      h2b, nullptr, N);
    // layer 2: h2b -> d_out (f32, no relu)
    agg_bf16<<<agrid, 256, 0, stream>>>((const u32*)h2b, row_start, colv, (u32*)aggb, N);
    gemm_mfma<false, true><<<ggrid, 256, 0, stream>>>(aggb, h2b, Wcat + 2 * D * 256, bl2,
                                                      nullptr, out, N);
}